// Round 7
// baseline (37.838 us; speedup 1.0000x reference)
//
#include <hip/hip_runtime.h>
#include <math.h>
#include <limits.h>
#include <stdint.h>

#define T_LEN 6000
#define B_ROWS 4096
#define PICK_WIN 20
#define BETA 25.0f

typedef float f4 __attribute__((ext_vector_type(4)));

// ---------------------------------------------------------------------------
// K1: 1 row per 128-thread block (grid 4096). 1500 float4/row:
// threads 0..91 own 12 slots, the rest 11 (slot 11 clamped in-row, skipped).
// 24 loads/thread (12 pred + 12 target), pair-interleaved in two asm blocks;
// consume pairs 0..5 at vmcnt(12) (12 loads still flying), pairs 6..11 at
// vmcnt(0). ~130-150 VGPR -> 3 waves/SIMD -> ~2.7 block generations per CU:
// later blocks' bursts overlap earlier blocks' reduce/pick tails (round 6 was
// exactly 1 generation -> tails ran with the memory system idle).
// No global atomics (r3/r4: same-line RMWs serialize at the coherence point).
// ---------------------------------------------------------------------------
__global__ __launch_bounds__(128) void row_pass1(const float* __restrict__ pred,
                                                 const float* __restrict__ target,
                                                 float* __restrict__ row_l1,
                                                 float* __restrict__ row_pick) {
    const int row  = blockIdx.x;
    const int tid  = threadIdx.x;
    const int wave = tid >> 6;
    const int lane = tid & 63;

    const uint64_t pb = (uint64_t)(pred   + (size_t)row * T_LEN);
    const uint64_t tb = (uint64_t)(target + (size_t)row * T_LEN);

    // 1500 = 11*128 + 92: threads 0..91 have a 12th slot.
    const bool has12 = (tid < (T_LEN / 4 - 11 * 128));   // tid < 92
    uint32_t va[12];
    #pragma unroll
    for (int k = 0; k < 11; ++k) va[k] = (uint32_t)(tid + k * 128) * 16u;
    va[11] = has12 ? (uint32_t)(tid + 11 * 128) * 16u
                   : (uint32_t)((T_LEN / 4 - 1) * 16);

    f4 p0, p1, p2, p3, p4, p5, p6, p7, p8, p9, p10, p11;
    f4 t0, t1, t2, t3, t4, t5, t6, t7, t8, t9, t10, t11;

    // pairs 0..5 (issue order p_k,t_k -> vmcnt counts pairs in order)
    asm volatile(
        "global_load_dwordx4 %0,  %12, %18\n\t"
        "global_load_dwordx4 %6,  %12, %19\n\t"
        "global_load_dwordx4 %1,  %13, %18\n\t"
        "global_load_dwordx4 %7,  %13, %19\n\t"
        "global_load_dwordx4 %2,  %14, %18\n\t"
        "global_load_dwordx4 %8,  %14, %19\n\t"
        "global_load_dwordx4 %3,  %15, %18\n\t"
        "global_load_dwordx4 %9,  %15, %19\n\t"
        "global_load_dwordx4 %4,  %16, %18\n\t"
        "global_load_dwordx4 %10, %16, %19\n\t"
        "global_load_dwordx4 %5,  %17, %18\n\t"
        "global_load_dwordx4 %11, %17, %19"
        : "=&v"(p0), "=&v"(p1), "=&v"(p2), "=&v"(p3), "=&v"(p4), "=&v"(p5),
          "=&v"(t0), "=&v"(t1), "=&v"(t2), "=&v"(t3), "=&v"(t4), "=&v"(t5)
        : "v"(va[0]), "v"(va[1]), "v"(va[2]), "v"(va[3]), "v"(va[4]), "v"(va[5]),
          "s"(pb), "s"(tb));
    // pairs 6..11
    asm volatile(
        "global_load_dwordx4 %0,  %12, %18\n\t"
        "global_load_dwordx4 %6,  %12, %19\n\t"
        "global_load_dwordx4 %1,  %13, %18\n\t"
        "global_load_dwordx4 %7,  %13, %19\n\t"
        "global_load_dwordx4 %2,  %14, %18\n\t"
        "global_load_dwordx4 %8,  %14, %19\n\t"
        "global_load_dwordx4 %3,  %15, %18\n\t"
        "global_load_dwordx4 %9,  %15, %19\n\t"
        "global_load_dwordx4 %4,  %16, %18\n\t"
        "global_load_dwordx4 %10, %16, %19\n\t"
        "global_load_dwordx4 %5,  %17, %18\n\t"
        "global_load_dwordx4 %11, %17, %19"
        : "=&v"(p6), "=&v"(p7), "=&v"(p8), "=&v"(p9), "=&v"(p10), "=&v"(p11),
          "=&v"(t6), "=&v"(t7), "=&v"(t8), "=&v"(t9), "=&v"(t10), "=&v"(t11)
        : "v"(va[6]), "v"(va[7]), "v"(va[8]), "v"(va[9]), "v"(va[10]), "v"(va[11]),
          "s"(pb), "s"(tb));

    float sum   = 0.0f;
    float bestv = -1.0f;            // |t| >= 0, always beaten
    int   besti = INT_MAX;

    // Indices strictly increase within a thread -> '>' keeps first occurrence.
#define CONSUME(PP, TT, K)                                                     \
    do {                                                                       \
        const int base = (tid + (K) * 128) * 4;                                \
        sum += fabsf(PP.x - TT.x) + fabsf(PP.y - TT.y) +                       \
               fabsf(PP.z - TT.z) + fabsf(PP.w - TT.w);                        \
        float a_;                                                              \
        a_ = fabsf(TT.x); if (a_ > bestv) { bestv = a_; besti = base;     }    \
        a_ = fabsf(TT.y); if (a_ > bestv) { bestv = a_; besti = base + 1; }    \
        a_ = fabsf(TT.z); if (a_ > bestv) { bestv = a_; besti = base + 2; }    \
        a_ = fabsf(TT.w); if (a_ > bestv) { bestv = a_; besti = base + 3; }    \
    } while (0)

    // pairs 0..5 ready once only the second asm block's 12 remain outstanding
    asm volatile("s_waitcnt vmcnt(12)" ::: "memory");
    __builtin_amdgcn_sched_barrier(0);
    CONSUME(p0, t0, 0);
    CONSUME(p1, t1, 1);
    CONSUME(p2, t2, 2);
    CONSUME(p3, t3, 3);
    CONSUME(p4, t4, 4);
    CONSUME(p5, t5, 5);

    asm volatile("s_waitcnt vmcnt(0)" ::: "memory");
    __builtin_amdgcn_sched_barrier(0);
    CONSUME(p6,  t6,  6);
    CONSUME(p7,  t7,  7);
    CONSUME(p8,  t8,  8);
    CONSUME(p9,  t9,  9);
    CONSUME(p10, t10, 10);
    if (has12) CONSUME(p11, t11, 11);
#undef CONSUME

    // ---- wave reduce: sum + argmax with tie -> min index
    #pragma unroll
    for (int o = 32; o > 0; o >>= 1) {
        sum += __shfl_xor(sum, o);
        const float ov = __shfl_xor(bestv, o);
        const int   oi = __shfl_xor(besti, o);
        if (ov > bestv || (ov == bestv && oi < besti)) { bestv = ov; besti = oi; }
    }

    __shared__ float s_sum[2];
    __shared__ float s_val[2];
    __shared__ int   s_idx[2];
    if (lane == 0) { s_sum[wave] = sum; s_val[wave] = bestv; s_idx[wave] = besti; }
    __syncthreads();

    // ---- wave 0: combine 2 partials, then the <=40-wide soft-argmax pick
    if (tid < 64) {
        float bs = s_sum[0] + s_sum[1];
        float bv = s_val[0];
        int   bi = s_idx[0];
        if (s_val[1] > bv || (s_val[1] == bv && s_idx[1] < bi)) {
            bv = s_val[1]; bi = s_idx[1];
        }

        const int c   = bi;
        const int s   = max(0, c - PICK_WIN);
        const int e   = min(T_LEN, c + PICK_WIN);
        const int len = e - s;

        float ap = -INFINITY, at = -INFINITY;
        const float posf = (float)(s + tid);
        if (tid < len) {
            const size_t idx = (size_t)row * T_LEN + s + tid;
            ap = BETA * fabsf(pred[idx]);     // L2-hot: just streamed
            at = BETA * fabsf(target[idx]);
        }

        float mp = ap, mt = at;
        #pragma unroll
        for (int o = 32; o > 0; o >>= 1) {
            mp = fmaxf(mp, __shfl_xor(mp, o));
            mt = fmaxf(mt, __shfl_xor(mt, o));
        }

        float wp = 0.0f, wt = 0.0f, wpp = 0.0f, wtp = 0.0f;
        if (tid < len) {
            wp  = expf(ap - mp);
            wt  = expf(at - mt);
            wpp = wp * posf;
            wtp = wt * posf;
        }
        #pragma unroll
        for (int o = 32; o > 0; o >>= 1) {
            wp  += __shfl_xor(wp,  o);
            wt  += __shfl_xor(wt,  o);
            wpp += __shfl_xor(wpp, o);
            wtp += __shfl_xor(wtp, o);
        }

        if (tid == 0) {
            row_l1[row]   = bs;
            row_pick[row] = fabsf(wpp / wp - wtp / wt);
        }
    }
}

// ---------------------------------------------------------------------------
// K2: deterministic final reduce + combine (1 block; float4 loads).
// ---------------------------------------------------------------------------
__global__ __launch_bounds__(256) void finalize(const float* __restrict__ row_l1,
                                                const float* __restrict__ row_pick,
                                                float* __restrict__ out) {
    const int tid  = threadIdx.x;
    const int wave = tid >> 6;
    const int lane = tid & 63;
    const f4* l4 = (const f4*)row_l1;
    const f4* p4 = (const f4*)row_pick;

    float a = 0.0f, b = 0.0f;
    #pragma unroll
    for (int k = 0; k < 4; ++k) {
        const f4 x = l4[tid + k * 256];
        const f4 y = p4[tid + k * 256];
        a += x.x + x.y + x.z + x.w;
        b += y.x + y.y + y.z + y.w;
    }
    #pragma unroll
    for (int o = 32; o > 0; o >>= 1) {
        a += __shfl_xor(a, o);
        b += __shfl_xor(b, o);
    }
    __shared__ float f1[4], f2[4];
    if (lane == 0) { f1[wave] = a; f2[wave] = b; }
    __syncthreads();
    if (tid == 0) {
        const float ta = f1[0] + f1[1] + f1[2] + f1[3];
        const float tb = f2[0] + f2[1] + f2[2] + f2[3];
        const float loss = ta / (float)((long long)B_ROWS * (long long)T_LEN);
        const float pick = (tb / (float)B_ROWS) / (float)T_LEN;
        out[0] = loss + 0.1f * pick;
    }
}

extern "C" void kernel_launch(void* const* d_in, const int* in_sizes, int n_in,
                              void* d_out, int out_size, void* d_ws, size_t ws_size,
                              hipStream_t stream) {
    const float* pred   = (const float*)d_in[0];
    const float* target = (const float*)d_in[1];
    float* out = (float*)d_out;

    // workspace layout: [row_l1: 4096 f32][row_pick: 4096 f32]
    float* row_l1   = (float*)d_ws;
    float* row_pick = row_l1 + B_ROWS;

    row_pass1<<<B_ROWS, 128, 0, stream>>>(pred, target, row_l1, row_pick);
    finalize<<<1, 256, 0, stream>>>(row_l1, row_pick, out);
}